// Round 1
// baseline (685.443 us; speedup 1.0000x reference)
//
#include <hip/hip_runtime.h>
#include <math.h>

#define D 128
#define NS 2048          // b*n = 2*1024
#define NCHUNK 16        // chunks per (b,layer) over n=1024
#define CLEN 64          // chunk length

__device__ __forceinline__ float sigmoidf_(float x) {
    return 1.0f / (1.0f + expf(-x));
}

// ---------------- Phase 1: per-sample forward/backward, rank-1 factors ----
// block = one sample, 128 threads
__global__ __launch_bounds__(128) void phase1(
    const float* __restrict__ seq, const float* __restrict__ W,
    const float* __restrict__ Wkv, const float* __restrict__ w_lr,
    float* __restrict__ ws_u, float* __restrict__ ws_g,
    float* __restrict__ lossbuf)
{
    const int s   = blockIdx.x;    // 0..2047
    const int tid = threadIdx.x;   // 0..127

    __shared__ float sseq[D], xbuf[D], vbuf[D];
    __shared__ float h0s[D], h1s[D], h2s[D];
    __shared__ float gbuf[D], red[D];

    sseq[tid] = seq[s * D + tid];
    __syncthreads();

    // scale = -(seq_row . w_lr)
    red[tid] = sseq[tid] * w_lr[tid];
    __syncthreads();
    for (int off = 64; off > 0; off >>= 1) {
        if (tid < off) red[tid] += red[tid + off];
        __syncthreads();
    }
    const float scale = -red[0];
    __syncthreads();   // protect red[0] before reuse

    // k, v = seq_row @ Wkv   (thread = output column, coalesced)
    float kacc = 0.f, vacc = 0.f;
    for (int r = 0; r < D; ++r) {
        float x = sseq[r];
        kacc += x * Wkv[r * 256 + tid];
        vacc += x * Wkv[r * 256 + 128 + tid];
    }
    xbuf[tid] = kacc;
    vbuf[tid] = vacc;
    ws_u[(s * 4 + 0) * D + tid] = kacc;   // u0 = k
    __syncthreads();

    // layer 0
    float h = 0.f;
    for (int r = 0; r < D; ++r) h += xbuf[r] * W[0 * 16384 + r * 128 + tid];
    h0s[tid] = h;
    {
        float a = h * sigmoidf_(h);
        __syncthreads();
        xbuf[tid] = a;
        ws_u[(s * 4 + 1) * D + tid] = a;  // u1 = a0
    }
    __syncthreads();

    // layer 1
    h = 0.f;
    for (int r = 0; r < D; ++r) h += xbuf[r] * W[1 * 16384 + r * 128 + tid];
    h1s[tid] = h;
    {
        float a = h * sigmoidf_(h);
        __syncthreads();
        xbuf[tid] = a;
        ws_u[(s * 4 + 2) * D + tid] = a;  // u2 = a1
    }
    __syncthreads();

    // layer 2
    h = 0.f;
    for (int r = 0; r < D; ++r) h += xbuf[r] * W[2 * 16384 + r * 128 + tid];
    h2s[tid] = h;
    {
        float a = h * sigmoidf_(h);
        __syncthreads();
        xbuf[tid] = a;
        ws_u[(s * 4 + 3) * D + tid] = a;  // u3 = a2
    }
    __syncthreads();

    // layer 3 (no activation) -> pred
    h = 0.f;
    for (int r = 0; r < D; ++r) h += xbuf[r] * W[3 * 16384 + r * 128 + tid];
    const float diff = h - vbuf[tid];

    // loss
    red[tid] = diff * diff;
    __syncthreads();
    for (int off = 64; off > 0; off >>= 1) {
        if (tid < off) red[tid] += red[tid + off];
        __syncthreads();
    }
    if (tid == 0) lossbuf[s] = red[0] * (1.0f / 128.0f);

    // backward
    float g = diff * (2.0f / 128.0f);           // g3
    gbuf[tid] = g;
    ws_g[(s * 4 + 3) * D + tid] = scale * g;
    __syncthreads();

    // da2 = W3[r,:] . g3 ; g2 = da2 * silu'(h2)
    float da = 0.f;
    for (int c = 0; c < D; ++c) da += W[3 * 16384 + tid * 128 + c] * gbuf[c];
    {
        float hv = h2s[tid];
        float sg = sigmoidf_(hv);
        g = da * (sg * (1.0f + hv * (1.0f - sg)));
    }
    __syncthreads();
    gbuf[tid] = g;
    ws_g[(s * 4 + 2) * D + tid] = scale * g;
    __syncthreads();

    // da1 with W2 ; g1 via h1
    da = 0.f;
    for (int c = 0; c < D; ++c) da += W[2 * 16384 + tid * 128 + c] * gbuf[c];
    {
        float hv = h1s[tid];
        float sg = sigmoidf_(hv);
        g = da * (sg * (1.0f + hv * (1.0f - sg)));
    }
    __syncthreads();
    gbuf[tid] = g;
    ws_g[(s * 4 + 1) * D + tid] = scale * g;
    __syncthreads();

    // da0 with W1 ; g0 via h0
    da = 0.f;
    for (int c = 0; c < D; ++c) da += W[1 * 16384 + tid * 128 + c] * gbuf[c];
    {
        float hv = h0s[tid];
        float sg = sigmoidf_(hv);
        g = da * (sg * (1.0f + hv * (1.0f - sg)));
    }
    ws_g[(s * 4 + 0) * D + tid] = scale * g;
}

// ---------------- Phase A: chunk sums (sum of 64 rank-1 products) ---------
// block = (b, layer, chunk); 256 threads, 64 accum elements each
__global__ __launch_bounds__(256) void phaseA(
    const float* __restrict__ ws_u, const float* __restrict__ ws_g,
    float* __restrict__ chunkS)
{
    const int cs    = blockIdx.x;       // 0..127
    const int j     = cs & 15;
    const int layer = (cs >> 4) & 3;
    const int b     = cs >> 6;
    const int tid   = threadIdx.x;

    __shared__ float us[D], gs[D];
    float acc[64];
#pragma unroll
    for (int k = 0; k < 64; ++k) acc[k] = 0.f;

    const int hi = tid >> 7;   // 0/1
    const int c  = tid & 127;

    for (int t = 0; t < CLEN; ++t) {
        const int samp = b * 1024 + j * CLEN + t;
        if (tid < 128) {
            us[tid] = ws_u[(samp * 4 + layer) * D + tid];
            gs[tid] = ws_g[(samp * 4 + layer) * D + tid];
        }
        __syncthreads();
        const float gv = gs[c];
#pragma unroll
        for (int k = 0; k < 64; ++k) acc[k] += us[2 * k + hi] * gv;
        __syncthreads();
    }
    float* out = chunkS + (size_t)cs * 16384;
#pragma unroll
    for (int k = 0; k < 64; ++k) out[k * 256 + tid] = acc[k];
}

// ---------------- Phase A2: exclusive scan of chunk sums (in place) -------
__global__ __launch_bounds__(256) void phaseA2(float* __restrict__ chunkS)
{
    const int g  = blockIdx.x * 256 + threadIdx.x;  // 0..131071
    const int bl = g >> 14;                         // (b,layer) 0..7
    const int e  = g & 16383;
    float* base = chunkS + (size_t)bl * NCHUNK * 16384 + e;
    float run = 0.f;
    for (int j = 0; j < NCHUNK; ++j) {
        float t = base[(size_t)j * 16384];
        base[(size_t)j * 16384] = run;
        run += t;
    }
}

// ---------------- Phase B: carry + rank-1 scan, stream grads --------------
// block = (b, layer, chunk, rowtile/4); 256 threads; tile 32 rows x 128 cols
__global__ __launch_bounds__(256) void phaseB(
    const float* __restrict__ ws_u, const float* __restrict__ ws_g,
    const float* __restrict__ chunkS, const float* __restrict__ W,
    float* __restrict__ out_grads, float* __restrict__ out_next)
{
    const int id    = blockIdx.x;         // 0..511
    const int rt    = id & 3;
    const int j     = (id >> 2) & 15;
    const int layer = (id >> 6) & 3;
    const int b     = id >> 8;
    const int cs    = (b * 4 + layer) * NCHUNK + j;
    const int tid   = threadIdx.x;

    const int c4 = (tid & 31) * 4;        // column (x4)
    const int rb = tid >> 5;              // 0..7
    const int r0 = rt * 32;

    __shared__ float us[32], gs[D];
    float4 acc[4];

    const float* carry = chunkS + (size_t)cs * 16384;
#pragma unroll
    for (int k = 0; k < 4; ++k) {
        int r = r0 + rb + 8 * k;
        acc[k] = *(const float4*)(carry + r * 128 + c4);
    }

    for (int t = 0; t < CLEN; ++t) {
        const int samp = b * 1024 + j * CLEN + t;
        if (tid < 128) {
            gs[tid] = ws_g[(samp * 4 + layer) * D + tid];
            if (tid < 32) us[tid] = ws_u[(samp * 4 + layer) * D + r0 + tid];
        }
        __syncthreads();
        float4 gv = *(const float4*)(gs + c4);
        float* obase = out_grads + ((size_t)samp * 4 + layer) * 16384;
#pragma unroll
        for (int k = 0; k < 4; ++k) {
            float uv = us[rb + 8 * k];
            acc[k].x += uv * gv.x;
            acc[k].y += uv * gv.y;
            acc[k].z += uv * gv.z;
            acc[k].w += uv * gv.w;
            int r = r0 + rb + 8 * k;
            *(float4*)(obase + r * 128 + c4) = acc[k];
        }
        __syncthreads();
    }

    if (j == NCHUNK - 1) {
#pragma unroll
        for (int k = 0; k < 4; ++k) {
            int r = r0 + rb + 8 * k;
            float4 w4 = *(const float4*)(W + layer * 16384 + r * 128 + c4);
            float4 o;
            o.x = acc[k].x + w4.x;
            o.y = acc[k].y + w4.y;
            o.z = acc[k].z + w4.z;
            o.w = acc[k].w + w4.w;
            *(float4*)(out_next + ((size_t)(b * 4 + layer)) * 16384 + r * 128 + c4) = o;
        }
    }
}

// ---------------- Loss reduction -----------------------------------------
__global__ __launch_bounds__(256) void lossk(const float* __restrict__ lossbuf,
                                             float* __restrict__ out)
{
    __shared__ float red[256];
    const int tid = threadIdx.x;
    float s = 0.f;
    for (int i = tid; i < NS; i += 256) s += lossbuf[i];
    red[tid] = s;
    __syncthreads();
    for (int off = 128; off > 0; off >>= 1) {
        if (tid < off) red[tid] += red[tid + off];
        __syncthreads();
    }
    if (tid == 0) out[0] = red[0] * (1.0f / (float)NS);
}

extern "C" void kernel_launch(void* const* d_in, const int* in_sizes, int n_in,
                              void* d_out, int out_size, void* d_ws, size_t ws_size,
                              hipStream_t stream)
{
    const float* seq   = (const float*)d_in[0];
    const float* W     = (const float*)d_in[1];
    const float* Wkv   = (const float*)d_in[2];
    const float* w_lr  = (const float*)d_in[3];
    // w_mom (d_in[4]) and w_decay (d_in[5]) do not affect any output.

    float* out = (float*)d_out;
    float* ws  = (float*)d_ws;

    float* ws_u    = ws;                         // 2048*4*128 = 1048576 floats
    float* ws_g    = ws + 1048576;               // 1048576 floats
    float* chunkS  = ws + 2097152;               // 128*16384 = 2097152 floats
    float* lossbuf = ws + 4194304;               // 2048 floats

    float* out_grads = out;                      // 134217728 floats
    float* out_next  = out + 134217728;          // 131072 floats
    float* out_loss  = out + 134348800;          // 1 float

    phase1<<<NS, 128, 0, stream>>>(seq, W, Wkv, w_lr, ws_u, ws_g, lossbuf);
    phaseA<<<128, 256, 0, stream>>>(ws_u, ws_g, chunkS);
    phaseA2<<<512, 256, 0, stream>>>(chunkS);
    phaseB<<<512, 256, 0, stream>>>(ws_u, ws_g, chunkS, W, out_grads, out_next);
    lossk<<<1, 256, 0, stream>>>(lossbuf, out_loss);
}